// Round 19
// baseline (297.408 us; speedup 1.0000x reference)
//
#include <hip/hip_runtime.h>
#include <hip/hip_bf16.h>
#include <stdint.h>

#define NNODES 100000
#define NEDGES 640000
#define CIN 128
#define EDIM 64
#define C2 256
#define LN_EPS 1e-5f
#define NW 6144            // gather waves (1536 blocks x 4) -- r5/r14 measured-best
#define PP 105             // ceil(NEDGES / NW)
#define NB 391             // scan blocks: 391*256 >= 100000

typedef __attribute__((ext_vector_type(8))) short bf16x8;
typedef __attribute__((ext_vector_type(4))) float f32x4;
typedef __attribute__((ext_vector_type(4))) uint32_t u32x4;
typedef __attribute__((ext_vector_type(4))) int i32x4;

__device__ __forceinline__ ushort f2bf(float f) {
    uint32_t u = __float_as_uint(f);
    uint32_t r = (u + 0x7fffu + ((u >> 16) & 1u)) >> 16;   // RNE
    return (ushort)r;
}
__device__ __forceinline__ ushort f2bf_u(uint32_t u) {     // RNE on raw f32 bits
    return (ushort)((u + 0x7fffu + ((u >> 16) & 1u)) >> 16);
}
__device__ __forceinline__ uint32_t pack2(float a, float b) {
    return (uint32_t)f2bf(a) | ((uint32_t)f2bf(b) << 16);
}
__device__ __forceinline__ float bf2f_lo(uint32_t u) { return __uint_as_float(u << 16); }
__device__ __forceinline__ float bf2f_hi(uint32_t u) { return __uint_as_float(u & 0xffff0000u); }

union U16 { uint4 u; bf16x8 v; };

// ---------------------------------------------------------------------------
// k_prep: (a) x -> bf16-packed xbf (k_edge gather + k23 A build); (b) W1,W2
// -> bf16 transposed in global; (c) zero cursor (captured memset = blit, r3).
// ---------------------------------------------------------------------------
__global__ __launch_bounds__(256) void k_prep(
    const float* __restrict__ x, const float* __restrict__ W1,
    const float* __restrict__ W2, uint32_t* __restrict__ xbf,
    ushort* __restrict__ W1T, ushort* __restrict__ W2T,
    int* __restrict__ cursor)
{
    const int bid = blockIdx.x;
    if (bid < 6250) {                                   // xbf: 1.6M threads
        const int i = bid * 256 + threadIdx.x;
        const float4* xg = (const float4*)x;
        const float4 v0 = xg[i * 2];
        const float4 v1 = xg[i * 2 + 1];
        uint4 o;
        o.x = pack2(v0.x, v0.y); o.y = pack2(v0.z, v0.w);
        o.z = pack2(v1.x, v1.y); o.w = pack2(v1.z, v1.w);
        ((uint4*)xbf)[i] = o;
    } else if (bid < 6506) {                            // weight transpose
        const int idx = (bid - 6250) * 256 + threadIdx.x;   // [0, 65536)
        if (idx < 32768) {
            const int k = idx >> 8, c = idx & 255;
            W1T[c * 128 + k] = f2bf(W1[idx]);
        } else {
            const int j = idx - 32768;
            const int k = j >> 7, c = j & 127;
            W2T[c * 256 + k] = f2bf(W2[j]);
        }
    } else {                                            // cursor zero
        const int n = (bid - 6506) * 256 + threadIdx.x;
        if (n < NNODES) cursor[n] = 0;
    }
}

// ---------------------------------------------------------------------------
// k_hist: degree histogram (int atomics into 400KB L2-resident array).
// ---------------------------------------------------------------------------
__global__ __launch_bounds__(256) void k_hist(const int* __restrict__ ei,
                                              int* __restrict__ counts)
{
    const int e = blockIdx.x * 256 + threadIdx.x;
    atomicAdd(&counts[ei[e]], 1);
}

// ---------------------------------------------------------------------------
// 2-phase coalesced exclusive scan: k_sA block sums; k_sC folds the bsum
// prefix (<=390 L2-hot ints per block) + in-block scan.
// ---------------------------------------------------------------------------
__global__ __launch_bounds__(256) void k_sA(const int* __restrict__ counts,
                                            int* __restrict__ bsum)
{
    const int t = threadIdx.x, lane = t & 63, wv = t >> 6;
    const int i = blockIdx.x * 256 + t;
    int s = (i < NNODES) ? counts[i] : 0;
#pragma unroll
    for (int off = 1; off < 64; off <<= 1) s += __shfl_xor(s, off);
    __shared__ int ws[4];
    if (lane == 0) ws[wv] = s;
    __syncthreads();
    if (t == 0) bsum[blockIdx.x] = ws[0] + ws[1] + ws[2] + ws[3];
}

__global__ __launch_bounds__(256) void k_sC(const int* __restrict__ bsum,
                                            int* __restrict__ cursor,
                                            int* __restrict__ rowptr)
{
    __shared__ int wred[4];
    __shared__ int ws[4];
    const int t = threadIdx.x, lane = t & 63, wv = t >> 6;

    // block offset = sum(bsum[j < blockIdx.x])
    int part = 0;
    for (int j = t; j < blockIdx.x; j += 256) part += bsum[j];
#pragma unroll
    for (int off = 1; off < 64; off <<= 1) part += __shfl_xor(part, off);
    if (lane == 0) wred[wv] = part;
    __syncthreads();
    const int blockoff = wred[0] + wred[1] + wred[2] + wred[3];

    const int i = blockIdx.x * 256 + t;
    const int v = (i < NNODES) ? cursor[i] : 0;
    int s = v;
#pragma unroll
    for (int off = 1; off < 64; off <<= 1) {
        const int u = __shfl_up(s, off);
        if (lane >= off) s += u;
    }
    if (lane == 63) ws[wv] = s;
    __syncthreads();
    int off0 = blockoff;
    for (int w = 0; w < wv; ++w) off0 += ws[w];
    const int excl = off0 + s - v;
    if (i < NNODES) { rowptr[i] = excl; cursor[i] = excl; }
    if (i == NNODES - 1) rowptr[NNODES] = excl + v;     // = NEDGES
}

// ---------------------------------------------------------------------------
// k_fillp: fill (blocks 0..2499; one int4 {e,src,dst,-} write per edge)
//          + node-aligned partition (2500..2524) + empty-node hbf zero.
// ---------------------------------------------------------------------------
__global__ __launch_bounds__(256) void k_fillp(const int* __restrict__ ei,
                                               int* __restrict__ cursor,
                                               int4* __restrict__ efs,
                                               const int* __restrict__ rowptr,
                                               int* __restrict__ naw,
                                               uint32_t* __restrict__ hbf)
{
    const int bid = blockIdx.x;
    if (bid < 2500) {
        const int e = bid * 256 + threadIdx.x;
        const int d = ei[e];
        const int pos = atomicAdd(&cursor[d], 1);
        int4 rec; rec.x = e; rec.y = ei[NEDGES + e]; rec.z = d; rec.w = 0;
        efs[pos] = rec;
    } else if (bid < 2525) {
        const int w = (bid - 2500) * 256 + threadIdx.x;
        if (w > NW) return;
        if (w == NW) { naw[w] = NNODES; return; }
        const int target = min(w * PP, NEDGES);
        int lo = 0, hi = NNODES;
        while (lo < hi) {
            const int mid = (lo + hi) >> 1;
            if (rowptr[mid] < target) lo = mid + 1; else hi = mid;
        }
        naw[w] = lo;
    } else {
        const int n = (bid - 2525) * 256 + threadIdx.x;
        if (n < NNODES && rowptr[n] == rowptr[n + 1]) {
            uint32_t* r = hbf + (size_t)n * 64;
#pragma unroll
            for (int i = 0; i < 64; ++i) r[i] = 0;
        }
    }
}

// ---------------------------------------------------------------------------
// k_edge: fused edge-GEMM + gather -- r14/r16 structure + NT loads on the
// read-once ea/efs streams. hbf store back to NORMAL (r18's NT store evicted
// hbf from L2 and k23 re-fetched it from HBM).
// ---------------------------------------------------------------------------
__global__ __launch_bounds__(256, 3) void k_edge(
    const uint32_t* __restrict__ xbf, const float* __restrict__ ea,
    const float* __restrict__ We, const float* __restrict__ be,
    const int4* __restrict__ efs, const int* __restrict__ naw,
    const int* __restrict__ rowptr, uint32_t* __restrict__ hbf)
{
    __shared__ float msgl[4 * 16 * 128];          // 32 KB: 8 KB per wave
    const int tid = threadIdx.x;
    const int l = tid & 63, q = l >> 4, m16 = l & 15;
    const int wv = tid >> 6;
    const int w = blockIdx.x * 4 + wv;

    // B fragments: bfw[ks][t][j] = We[k=ks*32+q*8+j][c=m16+16t]
    bf16x8 bfw[2][8];
#pragma unroll
    for (int ks = 0; ks < 2; ++ks)
#pragma unroll
        for (int t = 0; t < 8; ++t) {
            const int c = m16 + 16 * t;
#pragma unroll
            for (int j = 0; j < 8; ++j)
                bfw[ks][t][j] = (short)f2bf(We[(ks * 32 + q * 8 + j) * CIN + c]);
        }
    const float2 bev = ((const float2*)be)[l];

    const int n0 = naw[w], n1 = naw[w + 1];
    const int ps = rowptr[n0], pe = rowptr[n1];
    char* msb = (char*)msgl + wv * 8192;
    const int pmax = NEDGES - 1;

    int cur = -1;
    float a0 = 0.f, a1 = 0.f;

    for (int ts = ps; ts < pe; ts += 16) {
        const int nt = min(16, pe - ts);
        const int pp = min(ts + m16, pmax);
        const i32x4 rec = __builtin_nontemporal_load((const i32x4*)(efs + pp));
        const int ep = rec[0], sb = rec[1], db = rec[2];

        // ---- issue ea row FIRST (A-operand, consumed first), NT loads ----
        const u32x4* ar4 = (const u32x4*)(ea + (size_t)ep * EDIM + q * 8);
        const u32x4 uf0 = __builtin_nontemporal_load(ar4);
        const u32x4 uf1 = __builtin_nontemporal_load(ar4 + 1);
        const u32x4 ug0 = __builtin_nontemporal_load(ar4 + 8);   // +32 floats
        const u32x4 ug1 = __builtin_nontemporal_load(ar4 + 9);

        // ---- then the 16 independent bf16 x-gathers (cached, in flight) ----
        uint xr[16];
#pragma unroll
        for (int jj = 0; jj < 16; ++jj) {
            const int sj = __builtin_amdgcn_readlane(sb, jj);
            if (jj < nt) xr[jj] = xbf[(size_t)sj * 64 + l];
        }

        // ---- A-convert (waits ea only; rounds bf16 straight from bits) ----
        bf16x8 A0, A1;
        A0[0] = (short)f2bf_u(uf0[0]); A0[1] = (short)f2bf_u(uf0[1]);
        A0[2] = (short)f2bf_u(uf0[2]); A0[3] = (short)f2bf_u(uf0[3]);
        A0[4] = (short)f2bf_u(uf1[0]); A0[5] = (short)f2bf_u(uf1[1]);
        A0[6] = (short)f2bf_u(uf1[2]); A0[7] = (short)f2bf_u(uf1[3]);
        A1[0] = (short)f2bf_u(ug0[0]); A1[1] = (short)f2bf_u(ug0[1]);
        A1[2] = (short)f2bf_u(ug0[2]); A1[3] = (short)f2bf_u(ug0[3]);
        A1[4] = (short)f2bf_u(ug1[0]); A1[5] = (short)f2bf_u(ug1[1]);
        A1[6] = (short)f2bf_u(ug1[2]); A1[7] = (short)f2bf_u(ug1[3]);

        // ---- MFMA in two 64-col halves (acc = 16 VGPR) + LDS store ----
#pragma unroll
        for (int hf = 0; hf < 2; ++hf) {
            f32x4 acc4[4];
#pragma unroll
            for (int t4 = 0; t4 < 4; ++t4) acc4[t4] = (f32x4){0.f, 0.f, 0.f, 0.f};
#pragma unroll
            for (int t4 = 0; t4 < 4; ++t4) {
                acc4[t4] = __builtin_amdgcn_mfma_f32_16x16x32_bf16(A0, bfw[0][hf * 4 + t4], acc4[t4], 0, 0, 0);
                acc4[t4] = __builtin_amdgcn_mfma_f32_16x16x32_bf16(A1, bfw[1][hf * 4 + t4], acc4[t4], 0, 0, 0);
            }
#pragma unroll
            for (int t4 = 0; t4 < 4; ++t4) {
                const int col = m16 + 16 * (hf * 4 + t4);
#pragma unroll
                for (int r = 0; r < 4; ++r) {
                    const int row = q * 4 + r;
                    *(float*)(msb + row * 512 + ((4 * col) ^ ((row & 7) << 4))) = acc4[t4][r];
                }
            }
        }

        // ---- consume: relu(x + msg + be), accumulate, flush on node change --
#pragma unroll
        for (int jj = 0; jj < 16; ++jj) {
            if (jj < nt) {
                const int dj = __builtin_amdgcn_readlane(db, jj);
                if (dj != cur) {
                    if (cur >= 0)
                        hbf[(size_t)cur * 64 + l] = pack2(a0, a1);
                    cur = dj; a0 = 0.f; a1 = 0.f;
                }
                const uint32_t xu = xr[jj];
                const float2 mv = *(const float2*)(msb + jj * 512 + ((8 * l) ^ ((jj & 7) << 4)));
                a0 += fmaxf(bf2f_lo(xu) + mv.x + bev.x, 0.f);
                a1 += fmaxf(bf2f_hi(xu) + mv.y + bev.y, 0.f);
            }
        }
    }
    if (cur >= 0)
        hbf[(size_t)cur * 64 + l] = pack2(a0, a1);
}

// ---------------------------------------------------------------------------
// Fused MLP, BARRIER-FREE rebuild: GEMM1 B-frags straight from L2-hot global
// W1T (no LDS staging -- the 64KB stage + 3 barriers + 2-blocks/CU cap made
// the old version 94us at MfmaUtil 5%). LDS = wave-private h1 tiles only
// (8KB/wave, 32KB/block); each wave touches only its own slice -> no
// __syncthreads at all. 256-thread blocks, 64 rows each, 1563 blocks.
// ---------------------------------------------------------------------------
__global__ __launch_bounds__(256, 4) void k23_fused(
    const uint32_t* __restrict__ hbf, const uint32_t* __restrict__ xbf,
    const float* __restrict__ eps, const ushort* __restrict__ W1T,
    const ushort* __restrict__ W2T, const float* __restrict__ b1,
    const float* __restrict__ gamma, const float* __restrict__ beta,
    const float* __restrict__ b2, float* __restrict__ out)
{
    __shared__ ushort h1t[4 * 4096];      // 32 KB: 8 KB per wave (private)

    const int tid = threadIdx.x;
    const int l = tid & 63, q = l >> 4, m16 = l & 15;
    const int wv = tid >> 6;
    const int n0 = blockIdx.x * 64 + wv * 16;
    const int rowA = min(n0 + m16, NNODES - 1);
    const float s1p = 1.0f + eps[0];

    // ---- GEMM1: [16 x 128] @ [128 x 256]; A = (1+eps)x + msum on the fly;
    //      B-frags from global W1T (64KB, L2-hot across all blocks) ----
    f32x4 acc[16];
#pragma unroll
    for (int t = 0; t < 16; ++t) acc[t] = (f32x4){0.f, 0.f, 0.f, 0.f};

    const char* w1g = (const char*)W1T;
#pragma unroll
    for (int ks = 0; ks < 4; ++ks) {
        const uint4 su = *(const uint4*)(hbf + (size_t)rowA * 64 + ks * 16 + q * 4);
        const uint4 xu = *(const uint4*)(xbf + (size_t)rowA * 64 + ks * 16 + q * 4);
        U16 A;
        A.v[0] = (short)f2bf(fmaf(s1p, bf2f_lo(xu.x), bf2f_lo(su.x)));
        A.v[1] = (short)f2bf(fmaf(s1p, bf2f_hi(xu.x), bf2f_hi(su.x)));
        A.v[2] = (short)f2bf(fmaf(s1p, bf2f_lo(xu.y), bf2f_lo(su.y)));
        A.v[3] = (short)f2bf(fmaf(s1p, bf2f_hi(xu.y), bf2f_hi(su.y)));
        A.v[4] = (short)f2bf(fmaf(s1p, bf2f_lo(xu.z), bf2f_lo(su.z)));
        A.v[5] = (short)f2bf(fmaf(s1p, bf2f_hi(xu.z), bf2f_hi(su.z)));
        A.v[6] = (short)f2bf(fmaf(s1p, bf2f_lo(xu.w), bf2f_lo(su.w)));
        A.v[7] = (short)f2bf(fmaf(s1p, bf2f_hi(xu.w), bf2f_hi(su.w)));
        const int inrow = ks * 64 + q * 16;       // byte offset of k-slice
#pragma unroll
        for (int t = 0; t < 16; ++t) {
            U16 B; B.u = *(const uint4*)(w1g + (size_t)(m16 + 16 * t) * 256 + inrow);
            acc[t] = __builtin_amdgcn_mfma_f32_16x16x32_bf16(A.v, B.v, acc[t], 0, 0, 0);
        }
    }

    // ---- bias + LayerNorm + ReLU (in-register, 16-lane reduce) ----
    float s[4] = {0.f, 0.f, 0.f, 0.f}, sq[4] = {0.f, 0.f, 0.f, 0.f};
#pragma unroll
    for (int t = 0; t < 16; ++t) {
        const float bb = b1[m16 + 16 * t];
#pragma unroll
        for (int r = 0; r < 4; ++r) {
            acc[t][r] += bb;
            s[r]  += acc[t][r];
            sq[r] += acc[t][r] * acc[t][r];
        }
    }
#pragma unroll
    for (int off = 1; off < 16; off <<= 1)
#pragma unroll
        for (int r = 0; r < 4; ++r) {
            s[r]  += __shfl_xor(s[r],  off);
            sq[r] += __shfl_xor(sq[r], off);
        }
    float mu[4], is[4];
#pragma unroll
    for (int r = 0; r < 4; ++r) {
        mu[r] = s[r] * (1.0f / 256.0f);
        const float var = sq[r] * (1.0f / 256.0f) - mu[r] * mu[r];
        is[r] = rsqrtf(var + LN_EPS);
    }

    // ---- h1 tile (16 x 256 bf16) into wave-private LDS slice ----
    char* hls = (char*)h1t + wv * 8192;
#pragma unroll
    for (int t = 0; t < 16; ++t) {
        const int c = m16 + 16 * t;
        const float g = gamma[c], b = beta[c];
#pragma unroll
        for (int r = 0; r < 4; ++r) {
            const int row = q * 4 + r;
            const float o = fmaxf((acc[t][r] - mu[r]) * is[r] * g + b, 0.0f);
            *(ushort*)(hls + row * 512 + ((2 * c) ^ (row << 4))) = f2bf(o);
        }
    }
    // no barrier: same-wave ds_write -> ds_read ordered via lgkmcnt

    // ---- GEMM2: [16 x 256] @ [256 x 128], B from L2-hot W2T global ----
    f32x4 acc2[8];
#pragma unroll
    for (int t = 0; t < 8; ++t) acc2[t] = (f32x4){0.f, 0.f, 0.f, 0.f};

    const char* w2g = (const char*)W2T;
#pragma unroll
    for (int ks = 0; ks < 8; ++ks) {
        const int inrow = (ks * 64 + q * 16) ^ (m16 << 4);
        const int inrow2 = ks * 64 + q * 16;
        U16 A; A.u = *(const uint4*)(hls + m16 * 512 + inrow);
#pragma unroll
        for (int t = 0; t < 8; ++t) {
            U16 B; B.u = *(const uint4*)(w2g + (size_t)(m16 + 16 * t) * 512 + inrow2);
            acc2[t] = __builtin_amdgcn_mfma_f32_16x16x32_bf16(A.v, B.v, acc2[t], 0, 0, 0);
        }
    }
#pragma unroll
    for (int t = 0; t < 8; ++t) {
        const int c = m16 + 16 * t;
        const float bb = b2[c];
#pragma unroll
        for (int r = 0; r < 4; ++r) {
            const int row = n0 + q * 4 + r;
            if (row < NNODES)
                out[(size_t)row * CIN + c] = acc2[t][r] + bb;
        }
    }
}

// ---------------------------------------------------------------------------
extern "C" void kernel_launch(void* const* d_in, const int* in_sizes, int n_in,
                              void* d_out, int out_size, void* d_ws, size_t ws_size,
                              hipStream_t stream)
{
    const float* x     = (const float*)d_in[0];
    const int*   ei    = (const int*)d_in[1];
    const float* ea    = (const float*)d_in[2];
    const float* We    = (const float*)d_in[3];
    const float* be    = (const float*)d_in[4];
    const float* W1    = (const float*)d_in[5];
    const float* b1    = (const float*)d_in[6];
    const float* gamma = (const float*)d_in[7];
    const float* beta  = (const float*)d_in[8];
    const float* W2    = (const float*)d_in[9];
    const float* b2    = (const float*)d_in[10];
    const float* eps   = (const float*)d_in[11];

    // ws layout (16B-aligned), ~62.4 MB of ~655 MB:
    char* wsB = (char*)d_ws;
    uint32_t* hbf   = (uint32_t*)wsB;                       // 25,600,000 B
    int*      rowptr= (int*)(wsB + 25600000);               //    400,004 B
    int*      cursor= (int*)(wsB + 26001408);               //    400,000 B
    int4*     efs   = (int4*)(wsB + 26401408);              // 10,240,000 B
    int*      naw   = (int*)(wsB + 36641408);               //     24,580 B
    int*      bsum  = (int*)(wsB + 36666368);               //      1,564 B
    uint32_t* xbf   = (uint32_t*)(wsB + 36668416);          // 25,600,000 B
    ushort*   W1T   = (ushort*)(wsB + 62268416);            //     65,536 B
    ushort*   W2T   = (ushort*)(wsB + 62333952);            //     65,536 B

    k_prep <<<6897, 256, 0, stream>>>(x, W1, W2, xbf, W1T, W2T, cursor);
    k_hist <<<NEDGES / 256, 256, 0, stream>>>(ei, cursor);
    k_sA   <<<NB, 256, 0, stream>>>(cursor, bsum);
    k_sC   <<<NB, 256, 0, stream>>>(bsum, cursor, rowptr);
    k_fillp<<<2916, 256, 0, stream>>>(ei, cursor, efs, rowptr, naw, hbf);

    k_edge <<<NW / 4, 256, 0, stream>>>(xbf, ea, We, be, efs, naw,
                                        rowptr, hbf);

    k23_fused<<<(NNODES + 63) / 64, 256, 0, stream>>>(hbf, xbf, eps, W1T, W2T,
                                                      b1, gamma, beta, b2,
                                                      (float*)d_out);
}

// Round 20
// 263.894 us; speedup vs baseline: 1.1270x; 1.1270x over previous
//
#include <hip/hip_runtime.h>
#include <hip/hip_bf16.h>
#include <stdint.h>

#define NNODES 100000
#define NEDGES 640000
#define CIN 128
#define EDIM 64
#define C2 256
#define LN_EPS 1e-5f
#define NW 6144            // gather waves (1536 blocks x 4) -- r5/r14 measured-best
#define PP 105             // ceil(NEDGES / NW)
#define NB 391             // scan blocks: 391*256 >= 100000

typedef __attribute__((ext_vector_type(8))) short bf16x8;
typedef __attribute__((ext_vector_type(4))) float f32x4;
typedef __attribute__((ext_vector_type(4))) uint32_t u32x4;
typedef __attribute__((ext_vector_type(4))) int i32x4;

__device__ __forceinline__ ushort f2bf(float f) {
    uint32_t u = __float_as_uint(f);
    uint32_t r = (u + 0x7fffu + ((u >> 16) & 1u)) >> 16;   // RNE
    return (ushort)r;
}
__device__ __forceinline__ ushort f2bf_u(uint32_t u) {     // RNE on raw f32 bits
    return (ushort)((u + 0x7fffu + ((u >> 16) & 1u)) >> 16);
}
__device__ __forceinline__ uint32_t pack2(float a, float b) {
    return (uint32_t)f2bf(a) | ((uint32_t)f2bf(b) << 16);
}
__device__ __forceinline__ float bf2f_lo(uint32_t u) { return __uint_as_float(u << 16); }
__device__ __forceinline__ float bf2f_hi(uint32_t u) { return __uint_as_float(u & 0xffff0000u); }

union U16 { uint4 u; bf16x8 v; };

// ---------------------------------------------------------------------------
// k_prep: (a) x -> bf16-packed xbf (k_edge gather + k23 A build); (b) W1,W2
// -> bf16 transposed in global; (c) zero cursor (captured memset = blit, r3).
// ---------------------------------------------------------------------------
__global__ __launch_bounds__(256) void k_prep(
    const float* __restrict__ x, const float* __restrict__ W1,
    const float* __restrict__ W2, uint32_t* __restrict__ xbf,
    ushort* __restrict__ W1T, ushort* __restrict__ W2T,
    int* __restrict__ cursor)
{
    const int bid = blockIdx.x;
    if (bid < 6250) {                                   // xbf: 1.6M threads
        const int i = bid * 256 + threadIdx.x;
        const float4* xg = (const float4*)x;
        const float4 v0 = xg[i * 2];
        const float4 v1 = xg[i * 2 + 1];
        uint4 o;
        o.x = pack2(v0.x, v0.y); o.y = pack2(v0.z, v0.w);
        o.z = pack2(v1.x, v1.y); o.w = pack2(v1.z, v1.w);
        ((uint4*)xbf)[i] = o;
    } else if (bid < 6506) {                            // weight transpose
        const int idx = (bid - 6250) * 256 + threadIdx.x;   // [0, 65536)
        if (idx < 32768) {
            const int k = idx >> 8, c = idx & 255;
            W1T[c * 128 + k] = f2bf(W1[idx]);
        } else {
            const int j = idx - 32768;
            const int k = j >> 7, c = j & 127;
            W2T[c * 256 + k] = f2bf(W2[j]);
        }
    } else {                                            // cursor zero
        const int n = (bid - 6506) * 256 + threadIdx.x;
        if (n < NNODES) cursor[n] = 0;
    }
}

// ---------------------------------------------------------------------------
// k_hist: degree histogram (int atomics into 400KB L2-resident array).
// ---------------------------------------------------------------------------
__global__ __launch_bounds__(256) void k_hist(const int* __restrict__ ei,
                                              int* __restrict__ counts)
{
    const int e = blockIdx.x * 256 + threadIdx.x;
    atomicAdd(&counts[ei[e]], 1);
}

// ---------------------------------------------------------------------------
// 2-phase coalesced exclusive scan: k_sA block sums; k_sC folds the bsum
// prefix (<=390 L2-hot ints per block) + in-block scan.
// ---------------------------------------------------------------------------
__global__ __launch_bounds__(256) void k_sA(const int* __restrict__ counts,
                                            int* __restrict__ bsum)
{
    const int t = threadIdx.x, lane = t & 63, wv = t >> 6;
    const int i = blockIdx.x * 256 + t;
    int s = (i < NNODES) ? counts[i] : 0;
#pragma unroll
    for (int off = 1; off < 64; off <<= 1) s += __shfl_xor(s, off);
    __shared__ int ws[4];
    if (lane == 0) ws[wv] = s;
    __syncthreads();
    if (t == 0) bsum[blockIdx.x] = ws[0] + ws[1] + ws[2] + ws[3];
}

__global__ __launch_bounds__(256) void k_sC(const int* __restrict__ bsum,
                                            int* __restrict__ cursor,
                                            int* __restrict__ rowptr)
{
    __shared__ int wred[4];
    __shared__ int ws[4];
    const int t = threadIdx.x, lane = t & 63, wv = t >> 6;

    // block offset = sum(bsum[j < blockIdx.x])
    int part = 0;
    for (int j = t; j < blockIdx.x; j += 256) part += bsum[j];
#pragma unroll
    for (int off = 1; off < 64; off <<= 1) part += __shfl_xor(part, off);
    if (lane == 0) wred[wv] = part;
    __syncthreads();
    const int blockoff = wred[0] + wred[1] + wred[2] + wred[3];

    const int i = blockIdx.x * 256 + t;
    const int v = (i < NNODES) ? cursor[i] : 0;
    int s = v;
#pragma unroll
    for (int off = 1; off < 64; off <<= 1) {
        const int u = __shfl_up(s, off);
        if (lane >= off) s += u;
    }
    if (lane == 63) ws[wv] = s;
    __syncthreads();
    int off0 = blockoff;
    for (int w = 0; w < wv; ++w) off0 += ws[w];
    const int excl = off0 + s - v;
    if (i < NNODES) { rowptr[i] = excl; cursor[i] = excl; }
    if (i == NNODES - 1) rowptr[NNODES] = excl + v;     // = NEDGES
}

// ---------------------------------------------------------------------------
// k_fillp: fill (blocks 0..2499; one int4 {e,src,dst,-} write per edge)
//          + node-aligned partition (2500..2524) + empty-node hbf zero.
// ---------------------------------------------------------------------------
__global__ __launch_bounds__(256) void k_fillp(const int* __restrict__ ei,
                                               int* __restrict__ cursor,
                                               int4* __restrict__ efs,
                                               const int* __restrict__ rowptr,
                                               int* __restrict__ naw,
                                               uint32_t* __restrict__ hbf)
{
    const int bid = blockIdx.x;
    if (bid < 2500) {
        const int e = bid * 256 + threadIdx.x;
        const int d = ei[e];
        const int pos = atomicAdd(&cursor[d], 1);
        int4 rec; rec.x = e; rec.y = ei[NEDGES + e]; rec.z = d; rec.w = 0;
        efs[pos] = rec;
    } else if (bid < 2525) {
        const int w = (bid - 2500) * 256 + threadIdx.x;
        if (w > NW) return;
        if (w == NW) { naw[w] = NNODES; return; }
        const int target = min(w * PP, NEDGES);
        int lo = 0, hi = NNODES;
        while (lo < hi) {
            const int mid = (lo + hi) >> 1;
            if (rowptr[mid] < target) lo = mid + 1; else hi = mid;
        }
        naw[w] = lo;
    } else {
        const int n = (bid - 2525) * 256 + threadIdx.x;
        if (n < NNODES && rowptr[n] == rowptr[n + 1]) {
            uint32_t* r = hbf + (size_t)n * 64;
#pragma unroll
            for (int i = 0; i < 64; ++i) r[i] = 0;
        }
    }
}

// ---------------------------------------------------------------------------
// k_edge: fused edge-GEMM + gather -- r14/r16 structure + NT loads on the
// read-once ea/efs streams; normal hbf store (r18's NT store evicted hbf).
// ---------------------------------------------------------------------------
__global__ __launch_bounds__(256, 3) void k_edge(
    const uint32_t* __restrict__ xbf, const float* __restrict__ ea,
    const float* __restrict__ We, const float* __restrict__ be,
    const int4* __restrict__ efs, const int* __restrict__ naw,
    const int* __restrict__ rowptr, uint32_t* __restrict__ hbf)
{
    __shared__ float msgl[4 * 16 * 128];          // 32 KB: 8 KB per wave
    const int tid = threadIdx.x;
    const int l = tid & 63, q = l >> 4, m16 = l & 15;
    const int wv = tid >> 6;
    const int w = blockIdx.x * 4 + wv;

    // B fragments: bfw[ks][t][j] = We[k=ks*32+q*8+j][c=m16+16t]
    bf16x8 bfw[2][8];
#pragma unroll
    for (int ks = 0; ks < 2; ++ks)
#pragma unroll
        for (int t = 0; t < 8; ++t) {
            const int c = m16 + 16 * t;
#pragma unroll
            for (int j = 0; j < 8; ++j)
                bfw[ks][t][j] = (short)f2bf(We[(ks * 32 + q * 8 + j) * CIN + c]);
        }
    const float2 bev = ((const float2*)be)[l];

    const int n0 = naw[w], n1 = naw[w + 1];
    const int ps = rowptr[n0], pe = rowptr[n1];
    char* msb = (char*)msgl + wv * 8192;
    const int pmax = NEDGES - 1;

    int cur = -1;
    float a0 = 0.f, a1 = 0.f;

    for (int ts = ps; ts < pe; ts += 16) {
        const int nt = min(16, pe - ts);
        const int pp = min(ts + m16, pmax);
        const i32x4 rec = __builtin_nontemporal_load((const i32x4*)(efs + pp));
        const int ep = rec[0], sb = rec[1], db = rec[2];

        // ---- issue ea row FIRST (A-operand, consumed first), NT loads ----
        const u32x4* ar4 = (const u32x4*)(ea + (size_t)ep * EDIM + q * 8);
        const u32x4 uf0 = __builtin_nontemporal_load(ar4);
        const u32x4 uf1 = __builtin_nontemporal_load(ar4 + 1);
        const u32x4 ug0 = __builtin_nontemporal_load(ar4 + 8);   // +32 floats
        const u32x4 ug1 = __builtin_nontemporal_load(ar4 + 9);

        // ---- then the 16 independent bf16 x-gathers (cached, in flight) ----
        uint xr[16];
#pragma unroll
        for (int jj = 0; jj < 16; ++jj) {
            const int sj = __builtin_amdgcn_readlane(sb, jj);
            if (jj < nt) xr[jj] = xbf[(size_t)sj * 64 + l];
        }

        // ---- A-convert (waits ea only; rounds bf16 straight from bits) ----
        bf16x8 A0, A1;
        A0[0] = (short)f2bf_u(uf0[0]); A0[1] = (short)f2bf_u(uf0[1]);
        A0[2] = (short)f2bf_u(uf0[2]); A0[3] = (short)f2bf_u(uf0[3]);
        A0[4] = (short)f2bf_u(uf1[0]); A0[5] = (short)f2bf_u(uf1[1]);
        A0[6] = (short)f2bf_u(uf1[2]); A0[7] = (short)f2bf_u(uf1[3]);
        A1[0] = (short)f2bf_u(ug0[0]); A1[1] = (short)f2bf_u(ug0[1]);
        A1[2] = (short)f2bf_u(ug0[2]); A1[3] = (short)f2bf_u(ug0[3]);
        A1[4] = (short)f2bf_u(ug1[0]); A1[5] = (short)f2bf_u(ug1[1]);
        A1[6] = (short)f2bf_u(ug1[2]); A1[7] = (short)f2bf_u(ug1[3]);

        // ---- MFMA in two 64-col halves (acc = 16 VGPR) + LDS store ----
#pragma unroll
        for (int hf = 0; hf < 2; ++hf) {
            f32x4 acc4[4];
#pragma unroll
            for (int t4 = 0; t4 < 4; ++t4) acc4[t4] = (f32x4){0.f, 0.f, 0.f, 0.f};
#pragma unroll
            for (int t4 = 0; t4 < 4; ++t4) {
                acc4[t4] = __builtin_amdgcn_mfma_f32_16x16x32_bf16(A0, bfw[0][hf * 4 + t4], acc4[t4], 0, 0, 0);
                acc4[t4] = __builtin_amdgcn_mfma_f32_16x16x32_bf16(A1, bfw[1][hf * 4 + t4], acc4[t4], 0, 0, 0);
            }
#pragma unroll
            for (int t4 = 0; t4 < 4; ++t4) {
                const int col = m16 + 16 * (hf * 4 + t4);
#pragma unroll
                for (int r = 0; r < 4; ++r) {
                    const int row = q * 4 + r;
                    *(float*)(msb + row * 512 + ((4 * col) ^ ((row & 7) << 4))) = acc4[t4][r];
                }
            }
        }

        // ---- consume: relu(x + msg + be), accumulate, flush on node change --
#pragma unroll
        for (int jj = 0; jj < 16; ++jj) {
            if (jj < nt) {
                const int dj = __builtin_amdgcn_readlane(db, jj);
                if (dj != cur) {
                    if (cur >= 0)
                        hbf[(size_t)cur * 64 + l] = pack2(a0, a1);
                    cur = dj; a0 = 0.f; a1 = 0.f;
                }
                const uint32_t xu = xr[jj];
                const float2 mv = *(const float2*)(msb + jj * 512 + ((8 * l) ^ ((jj & 7) << 4)));
                a0 += fmaxf(bf2f_lo(xu) + mv.x + bev.x, 0.f);
                a1 += fmaxf(bf2f_hi(xu) + mv.y + bev.y, 0.f);
            }
        }
    }
    if (cur >= 0)
        hbf[(size_t)cur * 64 + l] = pack2(a0, a1);
}

// ---------------------------------------------------------------------------
// Fused MLP -- r13/r16-measured artifact (94us: 512 thr, W1T staged to LDS,
// h1 overlays w1t, W2T B-frags from global; r19's global-W1T rebuild was
// 150us) + ONE change: the 8 A-input loads (su/xu, 4 k-slices) are hoisted
// ABOVE the staging loop so their HBM latency hides under staging+barrier.
// ---------------------------------------------------------------------------
__global__ __launch_bounds__(512, 4) void k23_fused(
    const uint32_t* __restrict__ hbf, const uint32_t* __restrict__ xbf,
    const float* __restrict__ eps, const ushort* __restrict__ W1T,
    const ushort* __restrict__ W2T, const float* __restrict__ b1,
    const float* __restrict__ gamma, const float* __restrict__ beta,
    const float* __restrict__ b2, float* __restrict__ out)
{
    __shared__ ushort w1t[CIN * C2];      // 64 KB (then: h1 tiles, 8KB/wave)

    const int tid = threadIdx.x;
    const int l = tid & 63, q = l >> 4, m16 = l & 15;
    const int w = tid >> 6;
    const int n0 = blockIdx.x * 128 + w * 16;
    const int rowA = min(n0 + m16, NNODES - 1);

    // ---- hoisted A-input loads (latency hides under staging below) ----
    uint4 su[4], xu[4];
#pragma unroll
    for (int ks = 0; ks < 4; ++ks) {
        su[ks] = *(const uint4*)(hbf + (size_t)rowA * 64 + ks * 16 + q * 4);
        xu[ks] = *(const uint4*)(xbf + (size_t)rowA * 64 + ks * 16 + q * 4);
    }

    {   // stage W1T -> LDS, swizzled. 65536 B = 4096 chunks (8 iters/thread)
        const uint4* w1g = (const uint4*)W1T;
#pragma unroll
        for (int i = tid; i < 4096; i += 512) {
            const int c = i >> 4, inb = (i & 15) << 4;
            *(uint4*)((char*)w1t + c * 256 + (inb ^ ((c & 15) << 4))) = w1g[i];
        }
    }
    const float s1p = 1.0f + eps[0];
    __syncthreads();

    // ---- GEMM1: [16 x 128] @ [128 x 256], A = (1+eps)x + msum on the fly ----
    f32x4 acc[16];
#pragma unroll
    for (int t = 0; t < 16; ++t) acc[t] = (f32x4){0.f, 0.f, 0.f, 0.f};

    const char* w1b = (const char*)w1t;
#pragma unroll
    for (int ks = 0; ks < 4; ++ks) {
        U16 A;
        A.v[0] = (short)f2bf(fmaf(s1p, bf2f_lo(xu[ks].x), bf2f_lo(su[ks].x)));
        A.v[1] = (short)f2bf(fmaf(s1p, bf2f_hi(xu[ks].x), bf2f_hi(su[ks].x)));
        A.v[2] = (short)f2bf(fmaf(s1p, bf2f_lo(xu[ks].y), bf2f_lo(su[ks].y)));
        A.v[3] = (short)f2bf(fmaf(s1p, bf2f_hi(xu[ks].y), bf2f_hi(su[ks].y)));
        A.v[4] = (short)f2bf(fmaf(s1p, bf2f_lo(xu[ks].z), bf2f_lo(su[ks].z)));
        A.v[5] = (short)f2bf(fmaf(s1p, bf2f_hi(xu[ks].z), bf2f_hi(su[ks].z)));
        A.v[6] = (short)f2bf(fmaf(s1p, bf2f_lo(xu[ks].w), bf2f_lo(su[ks].w)));
        A.v[7] = (short)f2bf(fmaf(s1p, bf2f_hi(xu[ks].w), bf2f_hi(su[ks].w)));
        const int inrow = (ks * 64 + q * 16) ^ (m16 << 4);
#pragma unroll
        for (int t = 0; t < 16; ++t) {
            U16 B; B.u = *(const uint4*)(w1b + (size_t)(m16 + 16 * t) * 256 + inrow);
            acc[t] = __builtin_amdgcn_mfma_f32_16x16x32_bf16(A.v, B.v, acc[t], 0, 0, 0);
        }
    }

    // ---- bias + LayerNorm + ReLU (in-register, 16-lane reduce) ----
    float s[4] = {0.f, 0.f, 0.f, 0.f}, sq[4] = {0.f, 0.f, 0.f, 0.f};
#pragma unroll
    for (int t = 0; t < 16; ++t) {
        const float bb = b1[m16 + 16 * t];
#pragma unroll
        for (int r = 0; r < 4; ++r) {
            acc[t][r] += bb;
            s[r]  += acc[t][r];
            sq[r] += acc[t][r] * acc[t][r];
        }
    }
#pragma unroll
    for (int off = 1; off < 16; off <<= 1)
#pragma unroll
        for (int r = 0; r < 4; ++r) {
            s[r]  += __shfl_xor(s[r],  off);
            sq[r] += __shfl_xor(sq[r], off);
        }
    float mu[4], is[4];
#pragma unroll
    for (int r = 0; r < 4; ++r) {
        mu[r] = s[r] * (1.0f / 256.0f);
        const float var = sq[r] * (1.0f / 256.0f) - mu[r] * mu[r];
        is[r] = rsqrtf(var + LN_EPS);
    }

    __syncthreads();   // all waves done reading w1t -> safe to overwrite

    // ---- h1 tile (16 x 256 bf16) into own w1t slice ----
    char* hls = (char*)w1t + w * 8192;
#pragma unroll
    for (int t = 0; t < 16; ++t) {
        const int c = m16 + 16 * t;
        const float g = gamma[c], b = beta[c];
#pragma unroll
        for (int r = 0; r < 4; ++r) {
            const int row = q * 4 + r;
            const float o = fmaxf((acc[t][r] - mu[r]) * is[r] * g + b, 0.0f);
            *(ushort*)(hls + row * 512 + ((2 * c) ^ (row << 4))) = f2bf(o);
        }
    }
    __syncthreads();

    // ---- GEMM2: [16 x 256] @ [256 x 128], B from L2-hot W2T global ----
    f32x4 acc2[8];
#pragma unroll
    for (int t = 0; t < 8; ++t) acc2[t] = (f32x4){0.f, 0.f, 0.f, 0.f};

    const char* w2g = (const char*)W2T;
#pragma unroll
    for (int ks = 0; ks < 8; ++ks) {
        const int inrow = (ks * 64 + q * 16) ^ (m16 << 4);
        const int inrow2 = ks * 64 + q * 16;
        U16 A; A.u = *(const uint4*)(hls + m16 * 512 + inrow);
#pragma unroll
        for (int t = 0; t < 8; ++t) {
            U16 B; B.u = *(const uint4*)(w2g + (size_t)(m16 + 16 * t) * 512 + inrow2);
            acc2[t] = __builtin_amdgcn_mfma_f32_16x16x32_bf16(A.v, B.v, acc2[t], 0, 0, 0);
        }
    }
#pragma unroll
    for (int t = 0; t < 8; ++t) {
        const int c = m16 + 16 * t;
        const float bb = b2[c];
#pragma unroll
        for (int r = 0; r < 4; ++r) {
            const int row = n0 + q * 4 + r;
            if (row < NNODES)
                out[(size_t)row * CIN + c] = acc2[t][r] + bb;
        }
    }
}

// ---------------------------------------------------------------------------
extern "C" void kernel_launch(void* const* d_in, const int* in_sizes, int n_in,
                              void* d_out, int out_size, void* d_ws, size_t ws_size,
                              hipStream_t stream)
{
    const float* x     = (const float*)d_in[0];
    const int*   ei    = (const int*)d_in[1];
    const float* ea    = (const float*)d_in[2];
    const float* We    = (const float*)d_in[3];
    const float* be    = (const float*)d_in[4];
    const float* W1    = (const float*)d_in[5];
    const float* b1    = (const float*)d_in[6];
    const float* gamma = (const float*)d_in[7];
    const float* beta  = (const float*)d_in[8];
    const float* W2    = (const float*)d_in[9];
    const float* b2    = (const float*)d_in[10];
    const float* eps   = (const float*)d_in[11];

    // ws layout (16B-aligned), ~62.4 MB of ~655 MB:
    char* wsB = (char*)d_ws;
    uint32_t* hbf   = (uint32_t*)wsB;                       // 25,600,000 B
    int*      rowptr= (int*)(wsB + 25600000);               //    400,004 B
    int*      cursor= (int*)(wsB + 26001408);               //    400,000 B
    int4*     efs   = (int4*)(wsB + 26401408);              // 10,240,000 B
    int*      naw   = (int*)(wsB + 36641408);               //     24,580 B
    int*      bsum  = (int*)(wsB + 36666368);               //      1,564 B
    uint32_t* xbf   = (uint32_t*)(wsB + 36668416);          // 25,600,000 B
    ushort*   W1T   = (ushort*)(wsB + 62268416);            //     65,536 B
    ushort*   W2T   = (ushort*)(wsB + 62333952);            //     65,536 B

    k_prep <<<6897, 256, 0, stream>>>(x, W1, W2, xbf, W1T, W2T, cursor);
    k_hist <<<NEDGES / 256, 256, 0, stream>>>(ei, cursor);
    k_sA   <<<NB, 256, 0, stream>>>(cursor, bsum);
    k_sC   <<<NB, 256, 0, stream>>>(bsum, cursor, rowptr);
    k_fillp<<<2916, 256, 0, stream>>>(ei, cursor, efs, rowptr, naw, hbf);

    k_edge <<<NW / 4, 256, 0, stream>>>(xbf, ea, We, be, efs, naw,
                                        rowptr, hbf);

    k23_fused<<<(NNODES + 127) / 128, 512, 0, stream>>>(hbf, xbf, eps, W1T, W2T,
                                                        b1, gamma, beta, b2,
                                                        (float*)d_out);
}

// Round 21
// 249.627 us; speedup vs baseline: 1.1914x; 1.0572x over previous
//
#include <hip/hip_runtime.h>
#include <hip/hip_bf16.h>
#include <stdint.h>

#define NNODES 100000
#define NEDGES 640000
#define CIN 128
#define EDIM 64
#define C2 256
#define LN_EPS 1e-5f
#define NW 6144            // gather waves (1536 blocks x 4) -- r5 measured-best
#define PP 105             // ceil(NEDGES / NW)
#define NB 391             // scan blocks: 391*256 >= 100000

typedef __attribute__((ext_vector_type(8))) short bf16x8;
typedef __attribute__((ext_vector_type(4))) float f32x4;

__device__ __forceinline__ ushort f2bf(float f) {
    uint32_t u = __float_as_uint(f);
    uint32_t r = (u + 0x7fffu + ((u >> 16) & 1u)) >> 16;   // RNE
    return (ushort)r;
}
__device__ __forceinline__ uint32_t pack2(float a, float b) {
    return (uint32_t)f2bf(a) | ((uint32_t)f2bf(b) << 16);
}
__device__ __forceinline__ float bf2f_lo(uint32_t u) { return __uint_as_float(u << 16); }
__device__ __forceinline__ float bf2f_hi(uint32_t u) { return __uint_as_float(u & 0xffff0000u); }

union U16 { uint4 u; bf16x8 v; };

// ---------------------------------------------------------------------------
// k_prep: (a) x -> bf16-packed xbf (used by k_edge gather AND k23 A build);
// (b) W1,W2 -> transposed bf16 W1T[c][k], W2T[c][k] in global; (c) zero
// cursor (captured memset = blit path, ~91us, r3).
// ---------------------------------------------------------------------------
__global__ __launch_bounds__(256) void k_prep(
    const float* __restrict__ x, const float* __restrict__ W1,
    const float* __restrict__ W2, uint32_t* __restrict__ xbf,
    ushort* __restrict__ W1T, ushort* __restrict__ W2T,
    int* __restrict__ cursor)
{
    const int bid = blockIdx.x;
    if (bid < 6250) {                                   // xbf: 1.6M threads
        const int i = bid * 256 + threadIdx.x;
        const float4* xg = (const float4*)x;
        const float4 v0 = xg[i * 2];
        const float4 v1 = xg[i * 2 + 1];
        uint4 o;
        o.x = pack2(v0.x, v0.y); o.y = pack2(v0.z, v0.w);
        o.z = pack2(v1.x, v1.y); o.w = pack2(v1.z, v1.w);
        ((uint4*)xbf)[i] = o;
    } else if (bid < 6506) {                            // weight transpose
        const int idx = (bid - 6250) * 256 + threadIdx.x;   // [0, 65536)
        if (idx < 32768) {
            const int k = idx >> 8, c = idx & 255;
            W1T[c * 128 + k] = f2bf(W1[idx]);
        } else {
            const int j = idx - 32768;
            const int k = j >> 7, c = j & 127;
            W2T[c * 256 + k] = f2bf(W2[j]);
        }
    } else {                                            // cursor zero
        const int n = (bid - 6506) * 256 + threadIdx.x;
        if (n < NNODES) cursor[n] = 0;
    }
}

// ---------------------------------------------------------------------------
// k_hist: degree histogram (int atomics into 400KB L2-resident array).
// ---------------------------------------------------------------------------
__global__ __launch_bounds__(256) void k_hist(const int* __restrict__ ei,
                                              int* __restrict__ counts)
{
    const int e = blockIdx.x * 256 + threadIdx.x;
    atomicAdd(&counts[ei[e]], 1);
}

// ---------------------------------------------------------------------------
// Coalesced 3-phase exclusive scan of counts (cursor array). ~5-8us each.
// ---------------------------------------------------------------------------
__global__ __launch_bounds__(256) void k_sA(const int* __restrict__ counts,
                                            int* __restrict__ bsum)
{
    const int t = threadIdx.x, lane = t & 63, wv = t >> 6;
    const int i = blockIdx.x * 256 + t;
    int s = (i < NNODES) ? counts[i] : 0;
#pragma unroll
    for (int off = 1; off < 64; off <<= 1) s += __shfl_xor(s, off);
    __shared__ int ws[4];
    if (lane == 0) ws[wv] = s;
    __syncthreads();
    if (t == 0) bsum[blockIdx.x] = ws[0] + ws[1] + ws[2] + ws[3];
}

__global__ __launch_bounds__(512) void k_sB(int* __restrict__ bsum)
{
    const int t = threadIdx.x, lane = t & 63, wv = t >> 6;
    const int v = (t < NB) ? bsum[t] : 0;
    int s = v;
#pragma unroll
    for (int off = 1; off < 64; off <<= 1) {
        const int u = __shfl_up(s, off);
        if (lane >= off) s += u;
    }
    __shared__ int ws[8];
    if (lane == 63) ws[wv] = s;
    __syncthreads();
    int off0 = 0;
    for (int w = 0; w < wv; ++w) off0 += ws[w];
    if (t < NB) bsum[t] = off0 + s - v;                 // exclusive
}

__global__ __launch_bounds__(256) void k_sC(const int* __restrict__ bsum,
                                            int* __restrict__ cursor,
                                            int* __restrict__ rowptr)
{
    const int t = threadIdx.x, lane = t & 63, wv = t >> 6;
    const int i = blockIdx.x * 256 + t;
    const int v = (i < NNODES) ? cursor[i] : 0;
    int s = v;
#pragma unroll
    for (int off = 1; off < 64; off <<= 1) {
        const int u = __shfl_up(s, off);
        if (lane >= off) s += u;
    }
    __shared__ int ws[4];
    if (lane == 63) ws[wv] = s;
    __syncthreads();
    int off0 = bsum[blockIdx.x];
    for (int w = 0; w < wv; ++w) off0 += ws[w];
    const int excl = off0 + s - v;
    if (i < NNODES) { rowptr[i] = excl; cursor[i] = excl; }
    if (i == NNODES - 1) rowptr[NNODES] = excl + v;     // = NEDGES
}

// ---------------------------------------------------------------------------
// k_fillp: fill (blocks 0..2499; ONE int4 {e,src,dst,-} 16B scattered write
// per edge instead of 3x4B to 3 lines) + node-aligned partition (2500..2524)
// + empty-node hbf zero (2525..2915).
// ---------------------------------------------------------------------------
__global__ __launch_bounds__(256) void k_fillp(const int* __restrict__ ei,
                                               int* __restrict__ cursor,
                                               int4* __restrict__ efs,
                                               const int* __restrict__ rowptr,
                                               int* __restrict__ naw,
                                               uint32_t* __restrict__ hbf)
{
    const int bid = blockIdx.x;
    if (bid < 2500) {
        const int e = bid * 256 + threadIdx.x;
        const int d = ei[e];
        const int pos = atomicAdd(&cursor[d], 1);
        int4 rec; rec.x = e; rec.y = ei[NEDGES + e]; rec.z = d; rec.w = 0;
        efs[pos] = rec;
    } else if (bid < 2525) {
        const int w = (bid - 2500) * 256 + threadIdx.x;
        if (w > NW) return;
        if (w == NW) { naw[w] = NNODES; return; }
        const int target = min(w * PP, NEDGES);
        int lo = 0, hi = NNODES;
        while (lo < hi) {
            const int mid = (lo + hi) >> 1;
            if (rowptr[mid] < target) lo = mid + 1; else hi = mid;
        }
        naw[w] = lo;
    } else {
        const int n = (bid - 2525) * 256 + threadIdx.x;
        if (n < NNODES && rowptr[n] == rowptr[n + 1]) {
            uint32_t* r = hbf + (size_t)n * 64;
#pragma unroll
            for (int i = 0; i < 64; ++i) r[i] = 0;
        }
    }
}

// ---------------------------------------------------------------------------
// k_edge: fused edge-GEMM + gather. ea issued before the x-gathers (r13);
// gather from bf16 xbf (256B/row instead of 512B); int4 efs record.
// Structure otherwise the r5-measured one.
// ---------------------------------------------------------------------------
__global__ __launch_bounds__(256, 3) void k_edge(
    const uint32_t* __restrict__ xbf, const float* __restrict__ ea,
    const float* __restrict__ We, const float* __restrict__ be,
    const int4* __restrict__ efs, const int* __restrict__ naw,
    const int* __restrict__ rowptr, uint32_t* __restrict__ hbf)
{
    __shared__ float msgl[4 * 16 * 128];          // 32 KB: 8 KB per wave
    const int tid = threadIdx.x;
    const int l = tid & 63, q = l >> 4, m16 = l & 15;
    const int wv = tid >> 6;
    const int w = blockIdx.x * 4 + wv;

    // B fragments: bfw[ks][t][j] = We[k=ks*32+q*8+j][c=m16+16t]
    bf16x8 bfw[2][8];
#pragma unroll
    for (int ks = 0; ks < 2; ++ks)
#pragma unroll
        for (int t = 0; t < 8; ++t) {
            const int c = m16 + 16 * t;
#pragma unroll
            for (int j = 0; j < 8; ++j)
                bfw[ks][t][j] = (short)f2bf(We[(ks * 32 + q * 8 + j) * CIN + c]);
        }
    const float2 bev = ((const float2*)be)[l];

    const int n0 = naw[w], n1 = naw[w + 1];
    const int ps = rowptr[n0], pe = rowptr[n1];
    char* msb = (char*)msgl + wv * 8192;
    const int pmax = NEDGES - 1;

    int cur = -1;
    float a0 = 0.f, a1 = 0.f;

    for (int ts = ps; ts < pe; ts += 16) {
        const int nt = min(16, pe - ts);
        const int pp = min(ts + m16, pmax);
        const int4 rec = efs[pp];                 // {e, src, dst, -}
        const int ep = rec.x, sb = rec.y, db = rec.z;

        // ---- issue ea row FIRST (A-operand, consumed first) ----
        const float* ar = ea + (size_t)ep * EDIM + q * 8;
        const float4 f0 = *(const float4*)ar;
        const float4 f1 = *(const float4*)(ar + 4);
        const float4 g0 = *(const float4*)(ar + 32);
        const float4 g1 = *(const float4*)(ar + 36);

        // ---- then the 16 independent bf16 x-gathers (in flight over MFMA) --
        uint xr[16];
#pragma unroll
        for (int jj = 0; jj < 16; ++jj) {
            const int sj = __builtin_amdgcn_readlane(sb, jj);
            if (jj < nt) xr[jj] = xbf[(size_t)sj * 64 + l];
        }

        // ---- A-convert (waits ea only: vmcnt(16)) ----
        bf16x8 A0, A1;
        A0[0] = (short)f2bf(f0.x); A0[1] = (short)f2bf(f0.y);
        A0[2] = (short)f2bf(f0.z); A0[3] = (short)f2bf(f0.w);
        A0[4] = (short)f2bf(f1.x); A0[5] = (short)f2bf(f1.y);
        A0[6] = (short)f2bf(f1.z); A0[7] = (short)f2bf(f1.w);
        A1[0] = (short)f2bf(g0.x); A1[1] = (short)f2bf(g0.y);
        A1[2] = (short)f2bf(g0.z); A1[3] = (short)f2bf(g0.w);
        A1[4] = (short)f2bf(g1.x); A1[5] = (short)f2bf(g1.y);
        A1[6] = (short)f2bf(g1.z); A1[7] = (short)f2bf(g1.w);

        // ---- MFMA in two 64-col halves (acc = 16 VGPR) + LDS store ----
#pragma unroll
        for (int hf = 0; hf < 2; ++hf) {
            f32x4 acc4[4];
#pragma unroll
            for (int t4 = 0; t4 < 4; ++t4) acc4[t4] = (f32x4){0.f, 0.f, 0.f, 0.f};
#pragma unroll
            for (int t4 = 0; t4 < 4; ++t4) {
                acc4[t4] = __builtin_amdgcn_mfma_f32_16x16x32_bf16(A0, bfw[0][hf * 4 + t4], acc4[t4], 0, 0, 0);
                acc4[t4] = __builtin_amdgcn_mfma_f32_16x16x32_bf16(A1, bfw[1][hf * 4 + t4], acc4[t4], 0, 0, 0);
            }
#pragma unroll
            for (int t4 = 0; t4 < 4; ++t4) {
                const int col = m16 + 16 * (hf * 4 + t4);
#pragma unroll
                for (int r = 0; r < 4; ++r) {
                    const int row = q * 4 + r;
                    *(float*)(msb + row * 512 + ((4 * col) ^ ((row & 7) << 4))) = acc4[t4][r];
                }
            }
        }

        // ---- consume: relu(x + msg + be), accumulate, flush on node change --
#pragma unroll
        for (int jj = 0; jj < 16; ++jj) {
            if (jj < nt) {
                const int dj = __builtin_amdgcn_readlane(db, jj);
                if (dj != cur) {
                    if (cur >= 0)
                        hbf[(size_t)cur * 64 + l] = pack2(a0, a1);
                    cur = dj; a0 = 0.f; a1 = 0.f;
                }
                const uint32_t xu = xr[jj];
                const float2 mv = *(const float2*)(msb + jj * 512 + ((8 * l) ^ ((jj & 7) << 4)));
                a0 += fmaxf(bf2f_lo(xu) + mv.x + bev.x, 0.f);
                a1 += fmaxf(bf2f_hi(xu) + mv.y + bev.y, 0.f);
            }
        }
    }
    if (cur >= 0)
        hbf[(size_t)cur * 64 + l] = pack2(a0, a1);
}

// ---------------------------------------------------------------------------
// Fused MLP (r11/r13-measured artifact): one 128-row tile per block, 782
// blocks, W1T staged once. (r12's 2-tile loop spilled acc[16]: 358us.)
// ---------------------------------------------------------------------------
__global__ __launch_bounds__(512, 4) void k23_fused(
    const uint32_t* __restrict__ hbf, const uint32_t* __restrict__ xbf,
    const float* __restrict__ eps, const ushort* __restrict__ W1T,
    const ushort* __restrict__ W2T, const float* __restrict__ b1,
    const float* __restrict__ gamma, const float* __restrict__ beta,
    const float* __restrict__ b2, float* __restrict__ out)
{
    __shared__ ushort w1t[CIN * C2];      // 64 KB (then: h1 tiles, 8KB/wave)

    const int tid = threadIdx.x;
    {   // stage W1T -> LDS, swizzled. 65536 B = 4096 chunks (8 iters/thread)
        const uint4* w1g = (const uint4*)W1T;
#pragma unroll
        for (int i = tid; i < 4096; i += 512) {
            const int c = i >> 4, inb = (i & 15) << 4;
            *(uint4*)((char*)w1t + c * 256 + (inb ^ ((c & 15) << 4))) = w1g[i];
        }
    }
    const float s1p = 1.0f + eps[0];
    __syncthreads();

    const int l = tid & 63, q = l >> 4, m16 = l & 15;
    const int w = tid >> 6;
    const int n0 = blockIdx.x * 128 + w * 16;
    const int rowA = min(n0 + m16, NNODES - 1);

    // ---- GEMM1: [16 x 128] @ [128 x 256], A = (1+eps)x + msum on the fly ----
    f32x4 acc[16];
#pragma unroll
    for (int t = 0; t < 16; ++t) acc[t] = (f32x4){0.f, 0.f, 0.f, 0.f};

    const char* w1b = (const char*)w1t;
#pragma unroll
    for (int ks = 0; ks < 4; ++ks) {
        const uint4 su = *(const uint4*)(hbf + (size_t)rowA * 64 + ks * 16 + q * 4);
        const uint4 xu = *(const uint4*)(xbf + (size_t)rowA * 64 + ks * 16 + q * 4);
        U16 A;
        A.v[0] = (short)f2bf(fmaf(s1p, bf2f_lo(xu.x), bf2f_lo(su.x)));
        A.v[1] = (short)f2bf(fmaf(s1p, bf2f_hi(xu.x), bf2f_hi(su.x)));
        A.v[2] = (short)f2bf(fmaf(s1p, bf2f_lo(xu.y), bf2f_lo(su.y)));
        A.v[3] = (short)f2bf(fmaf(s1p, bf2f_hi(xu.y), bf2f_hi(su.y)));
        A.v[4] = (short)f2bf(fmaf(s1p, bf2f_lo(xu.z), bf2f_lo(su.z)));
        A.v[5] = (short)f2bf(fmaf(s1p, bf2f_hi(xu.z), bf2f_hi(su.z)));
        A.v[6] = (short)f2bf(fmaf(s1p, bf2f_lo(xu.w), bf2f_lo(su.w)));
        A.v[7] = (short)f2bf(fmaf(s1p, bf2f_hi(xu.w), bf2f_hi(su.w)));
        const int inrow = (ks * 64 + q * 16) ^ (m16 << 4);
#pragma unroll
        for (int t = 0; t < 16; ++t) {
            U16 B; B.u = *(const uint4*)(w1b + (size_t)(m16 + 16 * t) * 256 + inrow);
            acc[t] = __builtin_amdgcn_mfma_f32_16x16x32_bf16(A.v, B.v, acc[t], 0, 0, 0);
        }
    }

    // ---- bias + LayerNorm + ReLU (in-register, 16-lane reduce) ----
    float s[4] = {0.f, 0.f, 0.f, 0.f}, sq[4] = {0.f, 0.f, 0.f, 0.f};
#pragma unroll
    for (int t = 0; t < 16; ++t) {
        const float bb = b1[m16 + 16 * t];
#pragma unroll
        for (int r = 0; r < 4; ++r) {
            acc[t][r] += bb;
            s[r]  += acc[t][r];
            sq[r] += acc[t][r] * acc[t][r];
        }
    }
#pragma unroll
    for (int off = 1; off < 16; off <<= 1)
#pragma unroll
        for (int r = 0; r < 4; ++r) {
            s[r]  += __shfl_xor(s[r],  off);
            sq[r] += __shfl_xor(sq[r], off);
        }
    float mu[4], is[4];
#pragma unroll
    for (int r = 0; r < 4; ++r) {
        mu[r] = s[r] * (1.0f / 256.0f);
        const float var = sq[r] * (1.0f / 256.0f) - mu[r] * mu[r];
        is[r] = rsqrtf(var + LN_EPS);
    }

    __syncthreads();   // all waves done reading w1t -> safe to overwrite

    // ---- h1 tile (16 x 256 bf16) into own w1t slice ----
    char* hls = (char*)w1t + w * 8192;
#pragma unroll
    for (int t = 0; t < 16; ++t) {
        const int c = m16 + 16 * t;
        const float g = gamma[c], b = beta[c];
#pragma unroll
        for (int r = 0; r < 4; ++r) {
            const int row = q * 4 + r;
            const float o = fmaxf((acc[t][r] - mu[r]) * is[r] * g + b, 0.0f);
            *(ushort*)(hls + row * 512 + ((2 * c) ^ (row << 4))) = f2bf(o);
        }
    }
    __syncthreads();

    // ---- GEMM2: [16 x 256] @ [256 x 128], B from L2-hot W2T global ----
    f32x4 acc2[8];
#pragma unroll
    for (int t = 0; t < 8; ++t) acc2[t] = (f32x4){0.f, 0.f, 0.f, 0.f};

    const char* w2g = (const char*)W2T;
#pragma unroll
    for (int ks = 0; ks < 8; ++ks) {
        const int inrow = (ks * 64 + q * 16) ^ (m16 << 4);
        const int inrow2 = ks * 64 + q * 16;
        U16 A; A.u = *(const uint4*)(hls + m16 * 512 + inrow);
#pragma unroll
        for (int t = 0; t < 8; ++t) {
            U16 B; B.u = *(const uint4*)(w2g + (size_t)(m16 + 16 * t) * 512 + inrow2);
            acc2[t] = __builtin_amdgcn_mfma_f32_16x16x32_bf16(A.v, B.v, acc2[t], 0, 0, 0);
        }
    }
#pragma unroll
    for (int t = 0; t < 8; ++t) {
        const int c = m16 + 16 * t;
        const float bb = b2[c];
#pragma unroll
        for (int r = 0; r < 4; ++r) {
            const int row = n0 + q * 4 + r;
            if (row < NNODES)
                out[(size_t)row * CIN + c] = acc2[t][r] + bb;
        }
    }
}

// ---------------------------------------------------------------------------
extern "C" void kernel_launch(void* const* d_in, const int* in_sizes, int n_in,
                              void* d_out, int out_size, void* d_ws, size_t ws_size,
                              hipStream_t stream)
{
    const float* x     = (const float*)d_in[0];
    const int*   ei    = (const int*)d_in[1];
    const float* ea    = (const float*)d_in[2];
    const float* We    = (const float*)d_in[3];
    const float* be    = (const float*)d_in[4];
    const float* W1    = (const float*)d_in[5];
    const float* b1    = (const float*)d_in[6];
    const float* gamma = (const float*)d_in[7];
    const float* beta  = (const float*)d_in[8];
    const float* W2    = (const float*)d_in[9];
    const float* b2    = (const float*)d_in[10];
    const float* eps   = (const float*)d_in[11];

    // ws layout (16B-aligned), ~62.4 MB of ~655 MB:
    char* wsB = (char*)d_ws;
    uint32_t* hbf   = (uint32_t*)wsB;                       // 25,600,000 B
    int*      rowptr= (int*)(wsB + 25600000);               //    400,004 B
    int*      cursor= (int*)(wsB + 26001408);               //    400,000 B
    int4*     efs   = (int4*)(wsB + 26401408);              // 10,240,000 B
    int*      naw   = (int*)(wsB + 36641408);               //     24,580 B
    int*      bsum  = (int*)(wsB + 36666368);               //      1,564 B
    uint32_t* xbf   = (uint32_t*)(wsB + 36668416);          // 25,600,000 B
    ushort*   W1T   = (ushort*)(wsB + 62268416);            //     65,536 B
    ushort*   W2T   = (ushort*)(wsB + 62333952);            //     65,536 B

    k_prep <<<6897, 256, 0, stream>>>(x, W1, W2, xbf, W1T, W2T, cursor);
    k_hist <<<NEDGES / 256, 256, 0, stream>>>(ei, cursor);
    k_sA   <<<NB, 256, 0, stream>>>(cursor, bsum);
    k_sB   <<<1, 512, 0, stream>>>(bsum);
    k_sC   <<<NB, 256, 0, stream>>>(bsum, cursor, rowptr);
    k_fillp<<<2916, 256, 0, stream>>>(ei, cursor, efs, rowptr, naw, hbf);

    k_edge <<<NW / 4, 256, 0, stream>>>(xbf, ea, We, be, efs, naw,
                                        rowptr, hbf);

    k23_fused<<<(NNODES + 127) / 128, 512, 0, stream>>>(hbf, xbf, eps, W1T, W2T,
                                                        b1, gamma, beta, b2,
                                                        (float*)d_out);
}